// Round 2
// baseline (496.540 us; speedup 1.0000x reference)
//
#include <hip/hip_runtime.h>

typedef __attribute__((ext_vector_type(8))) short short8;
typedef __attribute__((ext_vector_type(4))) float f32x4;

#define B_ 64
#define H_ 24
#define N_ 32
#define F_ 256

__device__ __forceinline__ float bf2f(unsigned short u) {
    return __uint_as_float(((unsigned)u) << 16);
}
__device__ __forceinline__ unsigned short f2bf(float f) {
    unsigned u = __float_as_uint(f);
    u += 0x7fffu + ((u >> 16) & 1u);   // RNE
    return (unsigned short)(u >> 16);
}
// pack truncated-bf16(f0) into low16, truncated-bf16(f1) into high16
__device__ __forceinline__ unsigned pack_hi(float f0, float f1) {
    return (__float_as_uint(f0) >> 16) | (__float_as_uint(f1) & 0xffff0000u);
}
// residual after truncated-bf16: exact in fp32
__device__ __forceinline__ float res_lo(float f) {
    return f - __uint_as_float(__float_as_uint(f) & 0xffff0000u);
}

struct StageT {
    unsigned short Ah[64 * 32];   // 4 KB
    unsigned short Al[64 * 32];   // 4 KB
    unsigned short Wh[256 * 32];  // 16 KB
    unsigned short Wl[256 * 32];  // 16 KB
};
union Smem {
    StageT t;                     // 40 KB
    unsigned short outT[64 * 256];// 32 KB
};

// C[b][g] = sum_f A[b][f]*W[f][g], A fp32 rows at Ab + b*rstride, W fp32 [f][g].
// bf16 MFMA; SPLIT=true adds hi*lo + lo*hi passes (3xTF32-style) for accuracy.
template<bool SPLIT>
__device__ __forceinline__ void gemm_f32(
    const float* __restrict__ Ab, long rstride,
    const float* __restrict__ Wb, Smem& sm, f32x4 acc[4][4])
{
    const int t    = threadIdx.x;
    const int lane = t & 63;
    const int wv   = t >> 6;
    const int l15  = lane & 15;
    const int quad = lane >> 4;
    const int arow = t >> 2, achk = (t & 3) * 8;
    const float* aSrc = Ab + (long)arow * rstride + achk;

    for (int ks = 0; ks < 8; ks++) {
        const int k0 = ks * 32;
        __syncthreads();
        // ---- stage A tile (64 x 32 fp32 -> bf16 hi/lo) ----
        {
            float4 a0 = *(const float4*)(aSrc + k0);
            float4 a1 = *(const float4*)(aSrc + k0 + 4);
            uint4 h;
            h.x = pack_hi(a0.x, a0.y); h.y = pack_hi(a0.z, a0.w);
            h.z = pack_hi(a1.x, a1.y); h.w = pack_hi(a1.z, a1.w);
            *(uint4*)&sm.t.Ah[arow * 32 + achk] = h;
            if (SPLIT) {
                uint4 l;
                l.x = pack_hi(res_lo(a0.x), res_lo(a0.y));
                l.y = pack_hi(res_lo(a0.z), res_lo(a0.w));
                l.z = pack_hi(res_lo(a1.x), res_lo(a1.y));
                l.w = pack_hi(res_lo(a1.z), res_lo(a1.w));
                *(uint4*)&sm.t.Al[arow * 32 + achk] = l;
            }
        }
        // ---- stage W tile transposed: k = wv*8..+7, g = lane*4..+3 ----
        {
            union F4 { float4 v; float e[4]; } r[8];
            const float* wrow = Wb + (long)(k0 + wv * 8) * 256 + lane * 4;
            #pragma unroll
            for (int i = 0; i < 8; i++) r[i].v = *(const float4*)(wrow + i * 256);
            const int pos = wv ^ (lane & 3);   // xor-swizzled 16B chunk
            #pragma unroll
            for (int j = 0; j < 4; j++) {
                uint4 h;
                h.x = pack_hi(r[0].e[j], r[1].e[j]);
                h.y = pack_hi(r[2].e[j], r[3].e[j]);
                h.z = pack_hi(r[4].e[j], r[5].e[j]);
                h.w = pack_hi(r[6].e[j], r[7].e[j]);
                *(uint4*)&sm.t.Wh[(lane * 4 + j) * 32 + pos * 8] = h;
                if (SPLIT) {
                    uint4 l;
                    l.x = pack_hi(res_lo(r[0].e[j]), res_lo(r[1].e[j]));
                    l.y = pack_hi(res_lo(r[2].e[j]), res_lo(r[3].e[j]));
                    l.z = pack_hi(res_lo(r[4].e[j]), res_lo(r[5].e[j]));
                    l.w = pack_hi(res_lo(r[6].e[j]), res_lo(r[7].e[j]));
                    *(uint4*)&sm.t.Wl[(lane * 4 + j) * 32 + pos * 8] = l;
                }
            }
        }
        __syncthreads();
        // ---- fragments + MFMA ----
        short8 ah[4], bh[4];
        #pragma unroll
        for (int mi = 0; mi < 4; mi++)
            ah[mi] = *(const short8*)&sm.t.Ah[(mi * 16 + l15) * 32 + quad * 8];
        const int bpos = quad ^ ((l15 >> 2) & 3);
        #pragma unroll
        for (int ni = 0; ni < 4; ni++) {
            int g = wv * 64 + ni * 16 + l15;
            bh[ni] = *(const short8*)&sm.t.Wh[g * 32 + bpos * 8];
        }
        if (SPLIT) {
            short8 al[4], bl[4];
            #pragma unroll
            for (int mi = 0; mi < 4; mi++)
                al[mi] = *(const short8*)&sm.t.Al[(mi * 16 + l15) * 32 + quad * 8];
            #pragma unroll
            for (int ni = 0; ni < 4; ni++) {
                int g = wv * 64 + ni * 16 + l15;
                bl[ni] = *(const short8*)&sm.t.Wl[g * 32 + bpos * 8];
            }
            #pragma unroll
            for (int mi = 0; mi < 4; mi++)
                #pragma unroll
                for (int ni = 0; ni < 4; ni++) {
                    acc[mi][ni] = __builtin_amdgcn_mfma_f32_16x16x32_bf16(al[mi], bh[ni], acc[mi][ni], 0, 0, 0);
                    acc[mi][ni] = __builtin_amdgcn_mfma_f32_16x16x32_bf16(ah[mi], bl[ni], acc[mi][ni], 0, 0, 0);
                    acc[mi][ni] = __builtin_amdgcn_mfma_f32_16x16x32_bf16(ah[mi], bh[ni], acc[mi][ni], 0, 0, 0);
                }
        } else {
            #pragma unroll
            for (int mi = 0; mi < 4; mi++)
                #pragma unroll
                for (int ni = 0; ni < 4; ni++)
                    acc[mi][ni] = __builtin_amdgcn_mfma_f32_16x16x32_bf16(ah[mi], bh[ni], acc[mi][ni], 0, 0, 0);
        }
    }
}

// Kernel 1: qws[n][b][g] (fp32) = Q[b,n,:] @ Wq[n] + bq[n]
__global__ __launch_bounds__(256) void k_qproj(
    const float* __restrict__ Q, const float* __restrict__ Wq,
    const float* __restrict__ bq, float* __restrict__ qws)
{
    const int n = blockIdx.x;
    __shared__ Smem sm;
    f32x4 acc[4][4];
    #pragma unroll
    for (int i = 0; i < 4; i++)
        #pragma unroll
        for (int j = 0; j < 4; j++) acc[i][j] = (f32x4){0.f, 0.f, 0.f, 0.f};

    gemm_f32<true>(Q + n * F_, (long)(N_ * F_), Wq + (long)n * F_ * F_, sm, acc);

    const int t = threadIdx.x, lane = t & 63, wv = t >> 6;
    const int l15 = lane & 15, quad = lane >> 4;
    const float* bias = bq + n * F_;
    float* dst = qws + (long)n * (B_ * F_);
    #pragma unroll
    for (int ni = 0; ni < 4; ni++) {
        int g = wv * 64 + ni * 16 + l15;
        float bb = bias[g];
        #pragma unroll
        for (int mi = 0; mi < 4; mi++)
            #pragma unroll
            for (int reg = 0; reg < 4; reg++) {
                int r = mi * 16 + quad * 4 + reg;
                dst[r * 256 + g] = acc[mi][ni][reg] + bb;
            }
    }
}

// Kernel 2: grid (N*H, 2). y==0: KWk (split) + fused logits. y==1: VWv -> vws bf16.
__global__ __launch_bounds__(256) void k_kvproj(
    const float* __restrict__ Kx, const float* __restrict__ Vx,
    const float* __restrict__ Wk, const float* __restrict__ bk,
    const float* __restrict__ Wv, const float* __restrict__ bv,
    const float* __restrict__ qws, float* __restrict__ logits,
    unsigned short* __restrict__ vws)
{
    const int nh = blockIdx.x;
    const int n = nh / H_;
    const int h = nh - n * H_;
    const bool isV = (blockIdx.y != 0);
    const float* X    = isV ? Vx : Kx;
    const float* W    = (isV ? Wv : Wk) + (long)nh * F_ * F_;
    const float* bias = (isV ? bv : bk) + nh * F_;

    __shared__ Smem sm;
    __shared__ float slog[64];
    const int t = threadIdx.x;
    if (!isV && t < 64) slog[t] = 0.f;

    f32x4 acc[4][4];
    #pragma unroll
    for (int i = 0; i < 4; i++)
        #pragma unroll
        for (int j = 0; j < 4; j++) acc[i][j] = (f32x4){0.f, 0.f, 0.f, 0.f};

    if (isV) gemm_f32<false>(X + (long)(h * N_ + n) * F_, (long)(H_ * N_ * F_), W, sm, acc);
    else     gemm_f32<true >(X + (long)(h * N_ + n) * F_, (long)(H_ * N_ * F_), W, sm, acc);

    const int lane = t & 63, wv = t >> 6, l15 = lane & 15, quad = lane >> 4;

    if (!isV) {
        // logits[b] = sum_g qws[n,b,g] * (KWk[b,g] + bk[g])
        const float* qrow = qws + (long)n * (B_ * F_);
        #pragma unroll
        for (int mi = 0; mi < 4; mi++) {
            float p[4] = {0.f, 0.f, 0.f, 0.f};
            #pragma unroll
            for (int ni = 0; ni < 4; ni++) {
                int g = wv * 64 + ni * 16 + l15;
                float bb = bias[g];
                #pragma unroll
                for (int reg = 0; reg < 4; reg++) {
                    int r = mi * 16 + quad * 4 + reg;
                    p[reg] += (acc[mi][ni][reg] + bb) * qrow[r * 256 + g];
                }
            }
            #pragma unroll
            for (int off = 1; off < 16; off <<= 1)
                #pragma unroll
                for (int reg = 0; reg < 4; reg++)
                    p[reg] += __shfl_xor(p[reg], off, 64);
            if (l15 == 0)
                #pragma unroll
                for (int reg = 0; reg < 4; reg++)
                    atomicAdd(&slog[mi * 16 + quad * 4 + reg], p[reg]);
        }
        __syncthreads();
        if (t < 64) logits[(long)nh * 64 + t] = slog[t];
    } else {
        __syncthreads();   // frag reads done before overwriting smem
        #pragma unroll
        for (int ni = 0; ni < 4; ni++) {
            int g = wv * 64 + ni * 16 + l15;
            float bb = bias[g];
            #pragma unroll
            for (int mi = 0; mi < 4; mi++)
                #pragma unroll
                for (int reg = 0; reg < 4; reg++) {
                    int r = mi * 16 + quad * 4 + reg;
                    sm.outT[r * 256 + g] = f2bf(acc[mi][ni][reg] + bb);
                }
        }
        __syncthreads();
        unsigned short* dst = vws + (long)nh * (B_ * F_);
        #pragma unroll
        for (int it = 0; it < 8; it++) {
            int row = it * 8 + (t >> 5);
            int c = t & 31;
            uint4 v = *(const uint4*)(&sm.outT[row * 256 + c * 8]);
            *(uint4*)(dst + row * 256 + c * 8) = v;
        }
    }
}

// Kernel 3: per (b,n): softmax over H, write scores, combine VWv -> heads
__global__ __launch_bounds__(64) void k_attn(
    const float* __restrict__ logits,
    const unsigned short* __restrict__ vws,
    float* __restrict__ out)
{
    const int bx = blockIdx.x;
    const int b = bx >> 5;      // B=64
    const int n = bx & 31;      // N=32
    const int t = threadIdx.x;
    __shared__ float sl[24], se[24];
    if (t < 24) sl[t] = logits[(long)(n * H_ + t) * 64 + b];
    __syncthreads();
    float mx = -1e30f;
    #pragma unroll
    for (int h = 0; h < H_; h++) mx = fmaxf(mx, sl[h]);
    if (t < 24) se[t] = expf(sl[t] - mx);
    __syncthreads();
    float den = 0.f;
    #pragma unroll
    for (int h = 0; h < H_; h++) den += se[h];
    float inv = 1.0f / den;
    if (t < 24)
        out[(long)B_ * N_ * F_ + (long)(b * N_ + n) * H_ + t] = se[t] * inv;

    const int g0 = t * 4;
    float hv[4] = {0.f, 0.f, 0.f, 0.f};
    #pragma unroll
    for (int h = 0; h < H_; h++) {
        float s = se[h] * inv;
        const unsigned short* vp = vws + (((long)(n * H_ + h) * 64 + b) << 8) + g0;
        union { uint2 u; unsigned short e[4]; } vv;
        vv.u = *(const uint2*)vp;
        #pragma unroll
        for (int j = 0; j < 4; j++) hv[j] += s * bf2f(vv.e[j]);
    }
    float4 ov = make_float4(hv[0], hv[1], hv[2], hv[3]);
    *(float4*)(out + ((long)b * N_ + n) * F_ + g0) = ov;
}

extern "C" void kernel_launch(void* const* d_in, const int* in_sizes, int n_in,
                              void* d_out, int out_size, void* d_ws, size_t ws_size,
                              hipStream_t stream) {
    const float* Q  = (const float*)d_in[0];
    const float* K  = (const float*)d_in[1];
    const float* V  = (const float*)d_in[2];
    const float* Wq = (const float*)d_in[3];
    const float* bq = (const float*)d_in[4];
    const float* Wk = (const float*)d_in[5];
    const float* bk = (const float*)d_in[6];
    const float* Wv = (const float*)d_in[7];
    const float* bv = (const float*)d_in[8];

    char* ws = (char*)d_ws;
    float* qws          = (float*)ws;                               // N*B*F fp32 = 2 MB
    float* logits       = (float*)(ws + 2097152);                   // N*H*B fp32 = 192 KB
    unsigned short* vws = (unsigned short*)(ws + 2097152 + 262144); // N*H*B*F bf16 = 24 MB

    k_qproj<<<N_, 256, 0, stream>>>(Q, Wq, bq, qws);
    k_kvproj<<<dim3(N_ * H_, 2), 256, 0, stream>>>(K, V, Wk, bk, Wv, bv, qws, logits, vws);
    k_attn<<<B_ * N_, 64, 0, stream>>>(logits, vws, (float*)d_out);
}